// Round 1
// baseline (280.931 us; speedup 1.0000x reference)
//
#include <hip/hip_runtime.h>
#include <hip/hip_bf16.h>
#include <cstdint>
#include <cstddef>

#define NB   32
#define CIN  128
#define HH   56
#define WWD  56
#define HWP  3136          // 56*56
#define KOC  256
#define NRS  9

typedef __attribute__((ext_vector_type(8))) short short8;
typedef __attribute__((ext_vector_type(4))) float float4v;

__device__ __forceinline__ unsigned short f2bf(float f) {
    union { float f; unsigned int u; } v; v.f = f;
    unsigned int u = v.u;
    u = u + 0x7fffu + ((u >> 16) & 1u);   // RNE
    return (unsigned short)(u >> 16);
}

// ---------------------------------------------------------------------------
// W (OIHW fp32) -> Wt[rs][oc][c] bf16.  294912 elems, 1152 blocks x 256.
// ---------------------------------------------------------------------------
__global__ __launch_bounds__(256) void wt_kernel(const float* __restrict__ W,
                                                 unsigned short* __restrict__ wt) {
    int idx = blockIdx.x * 256 + threadIdx.x;          // rs<<15 | oc<<7 | c
    int c  = idx & 127;
    int oc = (idx >> 7) & 255;
    int rs = idx >> 15;
    wt[idx] = f2bf(W[((size_t)oc * CIN + c) * NRS + rs]);
}

// ---------------------------------------------------------------------------
// x NCHW fp32 -> XT[n][ck(4)][hw][32c] bf16.  Grid: 32*4*49 blocks x 256.
// Read coalesced along hw, LDS 32x(64+2) tile, write coalesced along c.
// ---------------------------------------------------------------------------
__global__ __launch_bounds__(256) void xpose_kernel(const float* __restrict__ x,
                                                    unsigned short* __restrict__ xt) {
    __shared__ unsigned short lds[32 * 66];
    int b   = blockIdx.x;
    int hwt = b % 49;
    int ck  = (b / 49) & 3;
    int n   = b / (49 * 4);
    int hw0 = hwt * 64;
    int t   = threadIdx.x;
    int col = t & 63;
    int q   = t >> 6;                                   // 0..3
    const float* src = x + ((size_t)(n * CIN + ck * 32)) * HWP + hw0;
    #pragma unroll
    for (int i = 0; i < 8; ++i) {
        int c = i * 4 + q;
        lds[c * 66 + col] = f2bf(src[(size_t)c * HWP + col]);
    }
    __syncthreads();
    int p   = t >> 2;
    int sub = t & 3;
    short8 v;
    #pragma unroll
    for (int j = 0; j < 8; ++j)
        v[j] = (short)lds[(sub * 8 + j) * 66 + p];
    size_t off = (((size_t)(n * 4 + ck)) * HWP + hw0 + p) * 32 + sub * 8;
    *(short8*)(xt + off) = v;
}

// ---------------------------------------------------------------------------
// Implicit GEMM: out[n][oc][hw] = sum_{rs,c} Wt[rs][oc][c] * XT[n][ck][hw'][cc]
// 128 oc x 128 px tile, BK=32, 4 waves (2x2), each wave 4x4 mfma 16x16x32.
// LDS layout: [chunk(4)][row(128)][8] shorts -> 16B-aligned b128 everywhere.
// ---------------------------------------------------------------------------
__global__ __launch_bounds__(256) void gemm_kernel(const unsigned short* __restrict__ xt,
                                                   const unsigned short* __restrict__ wt,
                                                   const float* __restrict__ bias,
                                                   float* __restrict__ out) {
    __shared__ unsigned short a_lds[4 * 128 * 8];
    __shared__ unsigned short b_lds[4 * 128 * 8];

    int bx  = blockIdx.x;                 // 25 pt x 32 n x 2 ot = 1600
    int ot  = bx & 1;
    int n   = (bx >> 1) & 31;
    int pt  = bx >> 6;
    int oc0 = ot * 128;
    int p0  = pt * 128;

    int t    = threadIdx.x;
    int wv   = t >> 6;
    int lane = t & 63;
    int lr   = lane & 15;
    int quad = lane >> 4;
    int wm   = wv >> 1;
    int wn   = wv & 1;

    // staging decomposition: each thread stages 2 x 16B for A and for B
    int chunk = t & 3;
    int row0  = t >> 2;                   // 0..63 (+64 on iter 1)

    int hw_[2], ph_[2], pw_[2];
    bool inb_[2];
    #pragma unroll
    for (int it = 0; it < 2; ++it) {
        int p  = row0 + it * 64;
        int hw = p0 + p;
        hw_[it]  = hw;
        inb_[it] = (hw < HWP);
        int h = hw / 56;
        ph_[it] = h;
        pw_[it] = hw - h * 56;
    }

    float4v acc[4][4];
    #pragma unroll
    for (int i = 0; i < 4; ++i)
        #pragma unroll
        for (int j = 0; j < 4; ++j)
            acc[i][j] = (float4v){0.f, 0.f, 0.f, 0.f};

    const unsigned short* xbase = xt + (size_t)n * 4 * HWP * 32;

    for (int rs = 0; rs < NRS; ++rs) {
        int dr    = rs / 3 - 1;
        int dc    = rs % 3 - 1;
        int shift = dr * 56 + dc;
        bool val[2];
        #pragma unroll
        for (int it = 0; it < 2; ++it)
            val[it] = inb_[it] &&
                      (unsigned)(ph_[it] + dr) < 56u &&
                      (unsigned)(pw_[it] + dc) < 56u;
        const unsigned short* wrow = wt + ((size_t)rs * KOC + oc0) * CIN;

        for (int ck = 0; ck < 4; ++ck) {
            __syncthreads();
            // ---- stage A (weights) ----
            #pragma unroll
            for (int it = 0; it < 2; ++it) {
                int row = row0 + it * 64;
                short8 av = *(const short8*)(wrow + (size_t)row * CIN + ck * 32 + chunk * 8);
                *(short8*)(a_lds + (chunk * 128 + row) * 8) = av;
            }
            // ---- stage B (activations) ----
            {
                const unsigned short* xck = xbase + (size_t)ck * (HWP * 32);
                #pragma unroll
                for (int it = 0; it < 2; ++it) {
                    int p = row0 + it * 64;
                    short8 bv = {0, 0, 0, 0, 0, 0, 0, 0};
                    if (val[it])
                        bv = *(const short8*)(xck + (size_t)(hw_[it] + shift) * 32 + chunk * 8);
                    *(short8*)(b_lds + (chunk * 128 + p) * 8) = bv;
                }
            }
            __syncthreads();
            // ---- compute ----
            short8 af[4], bf[4];
            #pragma unroll
            for (int i = 0; i < 4; ++i)
                af[i] = *(const short8*)(a_lds + (quad * 128 + wm * 64 + i * 16 + lr) * 8);
            #pragma unroll
            for (int j = 0; j < 4; ++j)
                bf[j] = *(const short8*)(b_lds + (quad * 128 + wn * 64 + j * 16 + lr) * 8);
            #pragma unroll
            for (int i = 0; i < 4; ++i)
                #pragma unroll
                for (int j = 0; j < 4; ++j)
                    acc[i][j] = __builtin_amdgcn_mfma_f32_16x16x32_bf16(
                        af[i], bf[j], acc[i][j], 0, 0, 0);
        }
    }

    // ---- epilogue: D row = oc (quad*4+reg), col = pixel (lane&15) ----
    float* orow = out + (size_t)n * KOC * HWP;
    #pragma unroll
    for (int i = 0; i < 4; ++i) {
        #pragma unroll
        for (int r = 0; r < 4; ++r) {
            int oc = oc0 + wm * 64 + i * 16 + quad * 4 + r;
            float bi = bias[oc];
            #pragma unroll
            for (int j = 0; j < 4; ++j) {
                int hw = p0 + wn * 64 + j * 16 + lr;
                if (hw < HWP)
                    orow[(size_t)oc * HWP + hw] = acc[i][j][r] + bi;
            }
        }
    }
}

// ---------------------------------------------------------------------------
// Safety fallback if ws is too small: naive direct conv (exact fp32).
// ---------------------------------------------------------------------------
__global__ void naive_kernel(const float* __restrict__ x, const float* __restrict__ W,
                             const float* __restrict__ b, float* __restrict__ out) {
    size_t idx = (size_t)blockIdx.x * 256 + threadIdx.x;
    if (idx >= (size_t)NB * KOC * HWP) return;
    int w0 = (int)(idx % 56);
    int h0 = (int)((idx / 56) % 56);
    int k  = (int)((idx / HWP) % KOC);
    int n  = (int)(idx / ((size_t)HWP * KOC));
    float acc = b[k];
    for (int c = 0; c < CIN; ++c) {
        const float* xr = x + ((size_t)n * CIN + c) * HWP;
        const float* wr = W + ((size_t)k * CIN + c) * NRS;
        for (int r = 0; r < 3; ++r) {
            int h = h0 + r - 1;
            if ((unsigned)h >= 56u) continue;
            for (int s = 0; s < 3; ++s) {
                int w = w0 + s - 1;
                if ((unsigned)w >= 56u) continue;
                acc += xr[h * 56 + w] * wr[r * 3 + s];
            }
        }
    }
    out[idx] = acc;
}

extern "C" void kernel_launch(void* const* d_in, const int* in_sizes, int n_in,
                              void* d_out, int out_size, void* d_ws, size_t ws_size,
                              hipStream_t stream) {
    const float* x  = (const float*)d_in[0];
    const float* W  = (const float*)d_in[1];
    const float* b  = (const float*)d_in[2];
    float* out = (float*)d_out;

    const size_t wt_elems = (size_t)NRS * KOC * CIN;            // 294912
    const size_t xt_elems = (size_t)NB * 4 * HWP * 32;          // 12845056
    const size_t need = (wt_elems + xt_elems) * sizeof(unsigned short);

    if (ws_size < need) {
        size_t total = (size_t)NB * KOC * HWP;
        naive_kernel<<<(unsigned)((total + 255) / 256), 256, 0, stream>>>(x, W, b, out);
        return;
    }

    unsigned short* wt = (unsigned short*)d_ws;
    unsigned short* xt = wt + wt_elems;                          // 589824 B offset, 16B-aligned

    wt_kernel<<<1152, 256, 0, stream>>>(W, wt);
    xpose_kernel<<<NB * 4 * 49, 256, 0, stream>>>(x, xt);
    gemm_kernel<<<1600, 256, 0, stream>>>(xt, wt, b, out);
}